// Round 8
// baseline (349.421 us; speedup 1.0000x reference)
//
#include <hip/hip_runtime.h>

// PointPillarScatter3d — R8 ABLATION ROUND.
// Dispatches: (1) linear write fill of d_out, (2) load-phase only (asm sink),
// (3) load+LDS-atomic only, (4) full R7 gather (correct output, runs last).
// Per-dispatch rocprof counters isolate which phase pins us at ~150us.

typedef float nfloat4 __attribute__((ext_vector_type(4)));

constexpr int NXc = 360;
constexpr int NYc = 360;
constexpr int NZc = 1;
constexpr int Cc  = 128;
constexpr int Bc  = 4;
constexpr int Sc  = NZc * NYc * NXc;   // 129600
constexpr int BSc = Bc * Sc;           // 518400

constexpr int TSC   = 540;             // cells per s-tile
constexpr int NST   = BSc / TSC;       // 960
constexpr int CHG   = 16;              // channels per block
constexpr int NCG   = Cc / CHG;        // 8
constexpr int CAP3  = 240;
constexpr int LSTR  = TSC + 1;         // 541
constexpr int CSTRIDE = 16;

// ---- fill: bin points into 540-cell s-tiles ---------------------------------
__global__ void pps_fill3(const int* __restrict__ coords,
                          int* __restrict__ cnt, int* __restrict__ list, int N) {
    int i = blockIdx.x * blockDim.x + threadIdx.x;
    if (i >= N) return;
    int4 c = reinterpret_cast<const int4*>(coords)[i];
    int g = c.x * Sc + c.y * (NYc * NXc) + c.z * NXc + c.w;
    int st = g / TSC;
    int cell = g - st * TSC;
    int slot = atomicAdd(&cnt[st * CSTRIDE], 1);
    if (slot < CAP3) list[st * CAP3 + slot] = (i << 10) | cell;
}

// ---- ABL 1: pure linear nontemporal write of the full output ----------------
__global__ __launch_bounds__(256)
void abl_wfill(float* __restrict__ out, int n4) {
    nfloat4 z = (nfloat4)0.0f;
    for (int i = blockIdx.x * blockDim.x + threadIdx.x; i < n4;
         i += gridDim.x * blockDim.x)
        __builtin_nontemporal_store(z, reinterpret_cast<nfloat4*>(out) + i);
}

// ---- ABL 2: load phase only (global reads kept live via asm sink) -----------
__global__ __launch_bounds__(512)
void abl_load(const float* __restrict__ feat,
              const int* __restrict__ cnt,
              const int* __restrict__ list) {
    __shared__ int slist[CAP3];
    __shared__ int sm;
    const int st = blockIdx.x >> 3;
    const int cg = blockIdx.x & 7;
    const int t  = threadIdx.x;
    if (t == 0) sm = min(cnt[st * CSTRIDE], CAP3);
    if (t < CAP3) slist[t] = list[st * CAP3 + t];
    __syncthreads();
    const int w = t >> 6, l = t & 63, psub = l >> 4, ch = l & 15;
    const int m = sm;
    #pragma unroll 2
    for (int sb = w * 4; sb < m; sb += 32) {
        int slot = sb + psub;
        bool ok = slot < m;
        int e = slist[ok ? slot : 0];
        int p = e >> 10;
        if (ok) {
            float v = feat[(size_t)p * Cc + cg * CHG + ch];
            asm volatile("" :: "v"(v));   // keep load, no store
        }
    }
}

// ---- ABL 3: load + LDS atomic accumulate (no global writes) -----------------
__global__ __launch_bounds__(512)
void abl_loadatomic(const float* __restrict__ feat,
                    const int* __restrict__ cnt,
                    const int* __restrict__ list) {
    __shared__ __align__(16) float lsum[CHG * LSTR];
    __shared__ int   lcnt[TSC];
    __shared__ int   slist[CAP3];
    __shared__ int   sm;
    const int st = blockIdx.x >> 3;
    const int cg = blockIdx.x & 7;
    const int t  = threadIdx.x;
    for (int k = t; k < (CHG * LSTR) / 4; k += 512)
        reinterpret_cast<nfloat4*>(lsum)[k] = (nfloat4)0.0f;
    for (int k = t; k < TSC; k += 512) lcnt[k] = 0;
    if (t == 0) sm = min(cnt[st * CSTRIDE], CAP3);
    if (t < CAP3) slist[t] = list[st * CAP3 + t];
    __syncthreads();
    const int w = t >> 6, l = t & 63, psub = l >> 4, ch = l & 15;
    const int m = sm;
    #pragma unroll 2
    for (int sb = w * 4; sb < m; sb += 32) {
        int slot = sb + psub;
        bool ok = slot < m;
        int e = slist[ok ? slot : 0];
        int cell = e & 1023;
        int p = e >> 10;
        if (ok) {
            float v = feat[(size_t)p * Cc + cg * CHG + ch];
            atomicAdd(&lsum[ch * LSTR + cell], v);
            if (ch == 0) atomicAdd(&lcnt[cell], 1);
        }
    }
    __syncthreads();
    // keep LDS result live without global traffic
    float x = lsum[t] + (float)lcnt[t & 511];
    asm volatile("" :: "v"(x));
}

// ---- full R7 gather (unchanged; produces correct output) --------------------
__global__ __launch_bounds__(512)
void pps_gather5(const float* __restrict__ feat,
                 const int* __restrict__ cnt,
                 const int* __restrict__ list,
                 float* __restrict__ out) {
    __shared__ __align__(16) float lsum[CHG * LSTR];
    __shared__ int   lcnt[TSC];
    __shared__ float linv[TSC];
    __shared__ int   slist[CAP3];
    __shared__ int   sm;

    const int st = blockIdx.x >> 3;
    const int cg = blockIdx.x & 7;
    const int t  = threadIdx.x;

    for (int k = t; k < (CHG * LSTR) / 4; k += 512)
        reinterpret_cast<nfloat4*>(lsum)[k] = (nfloat4)0.0f;
    for (int k = t; k < TSC; k += 512) lcnt[k] = 0;
    if (t == 0) sm = min(cnt[st * CSTRIDE], CAP3);
    if (t < CAP3) slist[t] = list[st * CAP3 + t];
    __syncthreads();

    const int w = t >> 6, l = t & 63, psub = l >> 4, ch = l & 15;
    const int m = sm;
    #pragma unroll 2
    for (int sb = w * 4; sb < m; sb += 32) {
        int slot = sb + psub;
        bool ok = slot < m;
        int e = slist[ok ? slot : 0];
        int cell = e & 1023;
        int p = e >> 10;
        if (ok) {
            float v = feat[(size_t)p * Cc + cg * CHG + ch];
            atomicAdd(&lsum[ch * LSTR + cell], v);
            if (ch == 0) atomicAdd(&lcnt[cell], 1);
        }
    }
    __syncthreads();

    for (int k = t; k < TSC; k += 512) {
        int n = lcnt[k];
        linv[k] = n > 0 ? 1.0f / (float)n : 0.0f;
    }
    __syncthreads();

    const int b  = st / (Sc / TSC);
    const int s0 = (st % (Sc / TSC)) * TSC;
    float* ob = out + ((size_t)b * Cc + cg * CHG) * Sc + s0;
    #pragma unroll
    for (int i = 0; i < 17; ++i) {
        int idx = i * 512 + t;
        if (idx < CHG * TSC) {
            int cl  = idx / TSC;
            int pos = idx - cl * TSC;
            float val = lsum[cl * LSTR + pos] * linv[pos];
            __builtin_nontemporal_store(val, ob + (size_t)cl * Sc + pos);
        }
    }
}

// ---- launch -----------------------------------------------------------------
extern "C" void kernel_launch(void* const* d_in, const int* in_sizes, int n_in,
                              void* d_out, int out_size, void* d_ws, size_t ws_size,
                              hipStream_t stream) {
    const float* feat   = reinterpret_cast<const float*>(d_in[0]);
    const int*   coords = reinterpret_cast<const int*>(d_in[1]);
    float*       out    = reinterpret_cast<float*>(d_out);

    const int N = in_sizes[0] / Cc;  // 160000

    const size_t cnt_bytes  = (size_t)NST * CSTRIDE * sizeof(int);
    int* cnt  = reinterpret_cast<int*>(d_ws);
    int* list = reinterpret_cast<int*>((char*)d_ws + cnt_bytes);

    (void)hipMemsetAsync(d_ws, 0, cnt_bytes, stream);
    {
        int threads = 256;
        int blocks = (N + threads - 1) / threads;
        pps_fill3<<<blocks, threads, 0, stream>>>(coords, cnt, list, N);
    }

    // --- ablation dispatches (full scale, output-safe) ---
    abl_wfill<<<2048, 256, 0, stream>>>(out, out_size / 4);          // 265 MB linear write
    abl_load<<<NST * NCG, 512, 0, stream>>>(feat, cnt, list);        // reads only
    abl_loadatomic<<<NST * NCG, 512, 0, stream>>>(feat, cnt, list);  // reads + LDS atomics

    // --- real kernel (overwrites every output element; runs last) ---
    pps_gather5<<<NST * NCG, 512, 0, stream>>>(feat, cnt, list, out);
}

// Round 9
// 147.566 us; speedup vs baseline: 2.3679x; 2.3679x over previous
//
#include <hip/hip_runtime.h>

// PointPillarScatter3d: scatter-mean of pillar features into BEV grid.
// R9 = R7 with ONE change: block index decomposition swapped to
//   bid = cg*NST + st  (channel-group OUTER, s-tile INNER)
// so concurrently-resident blocks write ~64 distinct output planes
// (near-sequential DRAM streams) instead of ~16k scattered streams.
// inputs: d_in[0]=pillar_features [N,128] fp32, d_in[1]=voxel_coords [N,4] int32 (b,z,y,x)
// output: bev [4, 128, 360, 360] fp32.

typedef float nfloat4 __attribute__((ext_vector_type(4)));

constexpr int NXc = 360;
constexpr int NYc = 360;
constexpr int NZc = 1;
constexpr int Cc  = 128;
constexpr int Bc  = 4;
constexpr int Sc  = NZc * NYc * NXc;   // 129600
constexpr int BSc = Bc * Sc;           // 518400

constexpr int TSC   = 540;             // cells per s-tile (no batch straddle: 129600/540=240)
constexpr int NST   = BSc / TSC;       // 960 s-tiles
constexpr int CHG   = 16;              // channels per block
constexpr int NCG   = Cc / CHG;        // 8 channel groups
constexpr int CAP3  = 240;             // max pts/s-tile (mean 166.7, sd 12.9)
constexpr int LSTR  = TSC + 1;         // 541
constexpr int CSTRIDE = 16;            // tile counters padded to 64B lines

// ---- fill: bin points into 540-cell s-tiles ---------------------------------
__global__ void pps_fill3(const int* __restrict__ coords,
                          int* __restrict__ cnt, int* __restrict__ list, int N) {
    int i = blockIdx.x * blockDim.x + threadIdx.x;
    if (i >= N) return;
    int4 c = reinterpret_cast<const int4*>(coords)[i];          // (b,z,y,x)
    int g = c.x * Sc + c.y * (NYc * NXc) + c.z * NXc + c.w;
    int st = g / TSC;
    int cell = g - st * TSC;
    int slot = atomicAdd(&cnt[st * CSTRIDE], 1);
    if (slot < CAP3) list[st * CAP3 + slot] = (i << 10) | cell; // i<2^18: fits
}

// ---- gather: block = s_tile x 16 channels; cg-outer grid order --------------
__global__ __launch_bounds__(512)
void pps_gather6(const float* __restrict__ feat,
                 const int* __restrict__ cnt,
                 const int* __restrict__ list,
                 float* __restrict__ out) {
    __shared__ __align__(16) float lsum[CHG * LSTR];   // 33.8 KB
    __shared__ int   lcnt[TSC];
    __shared__ float linv[TSC];
    __shared__ int   slist[CAP3];
    __shared__ int   sm;

    // THE R9 CHANGE: cg outer, st inner -> resident blocks share one cg and
    // cover consecutive s-tiles -> ~64 concurrent output planes device-wide.
    const int st = blockIdx.x % NST;
    const int cg = blockIdx.x / NST;
    const int t  = threadIdx.x;

    for (int k = t; k < (CHG * LSTR) / 4; k += 512)
        reinterpret_cast<nfloat4*>(lsum)[k] = (nfloat4)0.0f;
    for (int k = t; k < TSC; k += 512) lcnt[k] = 0;
    if (t == 0) sm = min(cnt[st * CSTRIDE], CAP3);
    if (t < CAP3) slist[t] = list[st * CAP3 + t];
    __syncthreads();

    // load phase: wave-instr = 4 points x 16 channels (64B per point).
    const int w = t >> 6, l = t & 63, psub = l >> 4, ch = l & 15;
    const int m = sm;
    #pragma unroll 2
    for (int sb = w * 4; sb < m; sb += 32) {
        int slot = sb + psub;
        bool ok = slot < m;
        int e = slist[ok ? slot : 0];
        int cell = e & 1023;
        int p = e >> 10;
        if (ok) {
            float v = feat[(size_t)p * Cc + cg * CHG + ch];
            atomicAdd(&lsum[ch * LSTR + cell], v);
            if (ch == 0) atomicAdd(&lcnt[cell], 1);
        }
    }
    __syncthreads();

    for (int k = t; k < TSC; k += 512) {
        int n = lcnt[k];
        linv[k] = n > 0 ? 1.0f / (float)n : 0.0f;
    }
    __syncthreads();

    // write phase: identical to R7 (scalar NT stores, stride-1 LDS reads)
    const int b  = st / (Sc / TSC);               // st/240
    const int s0 = (st % (Sc / TSC)) * TSC;
    float* ob = out + ((size_t)b * Cc + cg * CHG) * Sc + s0;
    #pragma unroll
    for (int i = 0; i < 17; ++i) {
        int idx = i * 512 + t;
        if (idx < CHG * TSC) {
            int cl  = idx / TSC;
            int pos = idx - cl * TSC;
            float val = lsum[cl * LSTR + pos] * linv[pos];
            __builtin_nontemporal_store(val, ob + (size_t)cl * Sc + pos);
        }
    }
}

// ---- fallback (R1 atomic scatter; used only if ws too small) ----------------
__global__ void pps_count_kernel(const int* __restrict__ coords,
                                 int* __restrict__ cnt, int N) {
    int i = blockIdx.x * blockDim.x + threadIdx.x;
    if (i >= N) return;
    int4 c = reinterpret_cast<const int4*>(coords)[i];
    int gidx = c.x * Sc + c.y * (NYc * NXc) + c.z * NXc + c.w;
    atomicAdd(&cnt[gidx], 1);
}

__global__ void pps_scatter_kernel(const float* __restrict__ feat,
                                   const int* __restrict__ coords,
                                   const int* __restrict__ cnt,
                                   float* __restrict__ out, int N) {
    int t = blockIdx.x * blockDim.x + threadIdx.x;
    int i = t >> 5;
    int g = t & 31;
    if (i >= N) return;
    int4 c = reinterpret_cast<const int4*>(coords)[i];
    int s    = c.y * (NYc * NXc) + c.z * NXc + c.w;
    int gidx = c.x * Sc + s;
    int n = cnt[gidx];
    float4 v = reinterpret_cast<const float4*>(feat + (size_t)i * Cc)[g];
    float* base = out + ((size_t)c.x * Cc + (size_t)g * 4) * Sc + s;
    if (n == 1) {
        base[0 * (size_t)Sc] = v.x;
        base[1 * (size_t)Sc] = v.y;
        base[2 * (size_t)Sc] = v.z;
        base[3 * (size_t)Sc] = v.w;
    } else {
        float inv = 1.0f / (float)n;
        atomicAdd(&base[0 * (size_t)Sc], v.x * inv);
        atomicAdd(&base[1 * (size_t)Sc], v.y * inv);
        atomicAdd(&base[2 * (size_t)Sc], v.z * inv);
        atomicAdd(&base[3 * (size_t)Sc], v.w * inv);
    }
}

// ---- launch -----------------------------------------------------------------
extern "C" void kernel_launch(void* const* d_in, const int* in_sizes, int n_in,
                              void* d_out, int out_size, void* d_ws, size_t ws_size,
                              hipStream_t stream) {
    const float* feat   = reinterpret_cast<const float*>(d_in[0]);
    const int*   coords = reinterpret_cast<const int*>(d_in[1]);
    float*       out    = reinterpret_cast<float*>(d_out);

    const int N = in_sizes[0] / Cc;  // 160000

    const size_t cnt_bytes  = (size_t)NST * CSTRIDE * sizeof(int);   // 61.4 KB
    const size_t list_bytes = (size_t)NST * CAP3 * sizeof(int);      // 921.6 KB

    if (ws_size >= cnt_bytes + list_bytes) {
        int* cnt  = reinterpret_cast<int*>(d_ws);
        int* list = reinterpret_cast<int*>((char*)d_ws + cnt_bytes);
        (void)hipMemsetAsync(d_ws, 0, cnt_bytes, stream);
        {
            int threads = 256;
            int blocks = (N + threads - 1) / threads;
            pps_fill3<<<blocks, threads, 0, stream>>>(coords, cnt, list, N);
        }
        pps_gather6<<<NST * NCG, 512, 0, stream>>>(feat, cnt, list, out);
    } else {
        int* cnt = reinterpret_cast<int*>(d_ws);
        (void)hipMemsetAsync(d_out, 0, (size_t)out_size * sizeof(float), stream);
        (void)hipMemsetAsync(d_ws, 0, (size_t)BSc * sizeof(int), stream);
        {
            int threads = 256;
            int blocks = (N + threads - 1) / threads;
            pps_count_kernel<<<blocks, threads, 0, stream>>>(coords, cnt, N);
        }
        {
            int threads = 256;
            long long total = (long long)N * 32;
            int blocks = (int)((total + threads - 1) / threads);
            pps_scatter_kernel<<<blocks, threads, 0, stream>>>(feat, coords, cnt, out, N);
        }
    }
}